// Round 14
// baseline (73.922 us; speedup 1.0000x reference)
//
#include <hip/hip_runtime.h>

#define B   16
#define C1  256          // channels per input
#define C2  512          // total channels after concat
#define HW  4096         // 64*64 pixels per channel
#define TCHUNK 32        // 128-pixel chunks per image

typedef float vf4 __attribute__((ext_vector_type(4)));

__device__ __forceinline__ const vf4* chan_base(
    const float* __restrict__ x1, const float* __restrict__ x2, int b, int c)
{
    return (const vf4*)((c < C1) ? (x1 + (size_t)(b * C1 + c) * HW)
                                 : (x2 + (size_t)(b * C1 + (c - C1)) * HW));
}

// ---------------------------------------------------------------------------
// K1: reduce with NONTEMPORAL loads (bypasses the L2-allocation wall:
// 45.5 -> ~25 us measured in round 13).
// ---------------------------------------------------------------------------
__global__ __launch_bounds__(256) void reduce_kernel(
    const float* __restrict__ x1, const float* __restrict__ x2,
    float* __restrict__ total, float* __restrict__ partials)
{
    int bid   = blockIdx.x;
    int b     = bid / TCHUNK;
    int chunk = bid % TCHUNK;
    int t     = threadIdx.x;
    int g     = t >> 5;
    int slot  = t & 31;
    int off   = chunk * 32 + slot;

    float* pp = partials + (size_t)(b * TCHUNK + chunk) * C2;
    vf4 t0 = (vf4)(0.f), t1 = (vf4)(0.f), t2 = (vf4)(0.f), t3 = (vf4)(0.f);

    for (int j = 0; j < 64; j += 4) {
        int c0 = (j + 0) * 8 + g, c1 = (j + 1) * 8 + g;
        int c2 = (j + 2) * 8 + g, c3 = (j + 3) * 8 + g;
        vf4 v0 = __builtin_nontemporal_load(chan_base(x1, x2, b, c0) + off);
        vf4 v1 = __builtin_nontemporal_load(chan_base(x1, x2, b, c1) + off);
        vf4 v2 = __builtin_nontemporal_load(chan_base(x1, x2, b, c2) + off);
        vf4 v3 = __builtin_nontemporal_load(chan_base(x1, x2, b, c3) + off);
        t0 += v0; t1 += v1; t2 += v2; t3 += v3;
        float h0 = (v0.x + v0.y) + (v0.z + v0.w);
        float h1 = (v1.x + v1.y) + (v1.z + v1.w);
        float h2 = (v2.x + v2.y) + (v2.z + v2.w);
        float h3 = (v3.x + v3.y) + (v3.z + v3.w);
        #pragma unroll
        for (int s = 16; s > 0; s >>= 1) {
            h0 += __shfl_down(h0, s, 32);
            h1 += __shfl_down(h1, s, 32);
            h2 += __shfl_down(h2, s, 32);
            h3 += __shfl_down(h3, s, 32);
        }
        if (slot == 0) { pp[c0] = h0; pp[c1] = h1; pp[c2] = h2; pp[c3] = h3; }
    }

    __shared__ vf4 red[8][32];
    red[g][slot] = (t0 + t1) + (t2 + t3);
    __syncthreads();
    if (g == 0) {
        vf4 r = (vf4)(0.f);
        #pragma unroll
        for (int gg = 0; gg < 8; ++gg) r += red[gg][slot];
        ((vf4*)(total + (size_t)b * HW))[off] = r;
    }
}

// ---------------------------------------------------------------------------
// K2: per-batch stable descending rank-sort (single dispatch, 16 blocks).
// ---------------------------------------------------------------------------
__global__ __launch_bounds__(512) void sort_kernel(
    const float* __restrict__ partials, int* __restrict__ idx)
{
    int b = blockIdx.x;
    int t = threadIdx.x;
    const float* pp = partials + (size_t)b * TCHUNK * C2 + t;
    float v = 0.f;
    #pragma unroll
    for (int ch = 0; ch < TCHUNK; ++ch) v += pp[ch * C2];
    __shared__ float sp[C2];
    sp[t] = v;
    __syncthreads();
    int rank = 0;
    for (int j = 0; j < C2; ++j) {
        float u = sp[j];
        rank += (u > v) || (u == v && j < t);
    }
    idx[b * C2 + rank] = t;
}

// ---------------------------------------------------------------------------
// K3: output — NT loads (same scattered-512B pattern as reduce, proven
// ~5 TB/s with nt) + NT stores. Channel k-1 = total - head_sum.
// ---------------------------------------------------------------------------
__global__ __launch_bounds__(256) void output_kernel(
    const float* __restrict__ x1, const float* __restrict__ x2,
    const int* __restrict__ idx, const float* __restrict__ total,
    float* __restrict__ out, int k)
{
    int bid   = blockIdx.x;
    int b     = bid / TCHUNK;
    int chunk = bid % TCHUNK;
    int t     = threadIdx.x;
    int g     = t >> 5;
    int slot  = t & 31;
    int off   = chunk * 32 + slot;
    int nh    = k - 1;

    __shared__ int ch[C2 / 2];
    __shared__ vf4 red[8][32];
    for (int i = t; i < nh; i += 256) ch[i] = idx[b * C2 + i];
    __syncthreads();

    vf4 a0 = (vf4)(0.f), a1 = (vf4)(0.f), a2 = (vf4)(0.f), a3 = (vf4)(0.f);
    const size_t ob = (size_t)b * k;
    int r = g;
    for (; r + 24 < nh; r += 32) {
        int c0 = ch[r], c1 = ch[r + 8], c2 = ch[r + 16], c3 = ch[r + 24];
        vf4 v0 = __builtin_nontemporal_load(chan_base(x1, x2, b, c0) + off);
        vf4 v1 = __builtin_nontemporal_load(chan_base(x1, x2, b, c1) + off);
        vf4 v2 = __builtin_nontemporal_load(chan_base(x1, x2, b, c2) + off);
        vf4 v3 = __builtin_nontemporal_load(chan_base(x1, x2, b, c3) + off);
        __builtin_nontemporal_store(v0, (vf4*)(out + (ob + r     ) * HW) + off);
        __builtin_nontemporal_store(v1, (vf4*)(out + (ob + r +  8) * HW) + off);
        __builtin_nontemporal_store(v2, (vf4*)(out + (ob + r + 16) * HW) + off);
        __builtin_nontemporal_store(v3, (vf4*)(out + (ob + r + 24) * HW) + off);
        a0 += v0; a1 += v1; a2 += v2; a3 += v3;
    }
    for (; r < nh; r += 8) {
        int c0 = ch[r];
        vf4 v0 = __builtin_nontemporal_load(chan_base(x1, x2, b, c0) + off);
        __builtin_nontemporal_store(v0, (vf4*)(out + (ob + r) * HW) + off);
        a0 += v0;
    }

    red[g][slot] = (a0 + a1) + (a2 + a3);
    __syncthreads();
    if (g == 0) {
        vf4 hsum = (vf4)(0.f);
        #pragma unroll
        for (int gg = 0; gg < 8; ++gg) hsum += red[gg][slot];
        vf4 tt = ((const vf4*)(total + (size_t)b * HW))[off];
        __builtin_nontemporal_store(tt - hsum,
                                    (vf4*)(out + (ob + (k - 1)) * HW) + off);
    }
}

// ---------------------------------------------------------------------------
extern "C" void kernel_launch(void* const* d_in, const int* in_sizes, int n_in,
                              void* d_out, int out_size, void* d_ws, size_t ws_size,
                              hipStream_t stream)
{
    const float* x1 = (const float*)d_in[0];
    const float* x2 = (const float*)d_in[1];
    float* out = (float*)d_out;

    int k = out_size / (B * HW);               // = 256

    int*   idx      = (int*)d_ws;
    float* total    = (float*)((char*)d_ws + B * C2 * sizeof(int));
    float* partials = total + (size_t)B * HW;

    reduce_kernel<<<B * TCHUNK, 256, 0, stream>>>(x1, x2, total, partials);
    sort_kernel<<<B, 512, 0, stream>>>(partials, idx);
    output_kernel<<<B * TCHUNK, 256, 0, stream>>>(x1, x2, idx, total, out, k);
}

// Round 15
// 65.646 us; speedup vs baseline: 1.1261x; 1.1261x over previous
//
#include <hip/hip_runtime.h>

#define B   16
#define C1  256          // channels per input
#define C2  512          // total channels after concat
#define HW  4096         // 64*64 pixels per channel
#define TCHUNK 32        // 128-pixel chunks per image

typedef float vf4 __attribute__((ext_vector_type(4)));

// x1 channels: NORMAL loads (allocate -> warm L2/L3 for the output pass).
// x2 channels: NONTEMPORAL loads (fast cold path, ~5.1 TB/s, no pollution).
__device__ __forceinline__ vf4 load_chan(
    const float* __restrict__ x1, const float* __restrict__ x2,
    int b, int c, int off)
{
    if (c < C1)
        return ((const vf4*)(x1 + (size_t)(b * C1 + c) * HW))[off];
    return __builtin_nontemporal_load(
        (const vf4*)(x2 + (size_t)(b * C1 + (c - C1)) * HW) + off);
}

// ---------------------------------------------------------------------------
// K1: reduce. Block = (b, 128-pixel chunk); 8 channel-groups x 32 slots.
// x1 half via normal loads (warms caches), x2 half via NT loads (fast).
// ---------------------------------------------------------------------------
__global__ __launch_bounds__(256) void reduce_kernel(
    const float* __restrict__ x1, const float* __restrict__ x2,
    float* __restrict__ total, float* __restrict__ partials)
{
    int bid   = blockIdx.x;
    int b     = bid / TCHUNK;
    int chunk = bid % TCHUNK;
    int t     = threadIdx.x;
    int g     = t >> 5;
    int slot  = t & 31;
    int off   = chunk * 32 + slot;

    float* pp = partials + (size_t)(b * TCHUNK + chunk) * C2;
    vf4 t0 = (vf4)(0.f), t1 = (vf4)(0.f), t2 = (vf4)(0.f), t3 = (vf4)(0.f);

    // ---- x1 half: channels 0..255 (j = 0..31), NORMAL loads ----
    for (int j = 0; j < 32; j += 4) {
        int c0 = (j + 0) * 8 + g, c1 = (j + 1) * 8 + g;
        int c2 = (j + 2) * 8 + g, c3 = (j + 3) * 8 + g;
        vf4 v0 = ((const vf4*)(x1 + (size_t)(b * C1 + c0) * HW))[off];
        vf4 v1 = ((const vf4*)(x1 + (size_t)(b * C1 + c1) * HW))[off];
        vf4 v2 = ((const vf4*)(x1 + (size_t)(b * C1 + c2) * HW))[off];
        vf4 v3 = ((const vf4*)(x1 + (size_t)(b * C1 + c3) * HW))[off];
        t0 += v0; t1 += v1; t2 += v2; t3 += v3;
        float h0 = (v0.x + v0.y) + (v0.z + v0.w);
        float h1 = (v1.x + v1.y) + (v1.z + v1.w);
        float h2 = (v2.x + v2.y) + (v2.z + v2.w);
        float h3 = (v3.x + v3.y) + (v3.z + v3.w);
        #pragma unroll
        for (int s = 16; s > 0; s >>= 1) {
            h0 += __shfl_down(h0, s, 32);
            h1 += __shfl_down(h1, s, 32);
            h2 += __shfl_down(h2, s, 32);
            h3 += __shfl_down(h3, s, 32);
        }
        if (slot == 0) { pp[c0] = h0; pp[c1] = h1; pp[c2] = h2; pp[c3] = h3; }
    }

    // ---- x2 half: channels 256..511 (j = 32..63), NT loads ----
    for (int j = 32; j < 64; j += 4) {
        int c0 = (j + 0) * 8 + g, c1 = (j + 1) * 8 + g;
        int c2 = (j + 2) * 8 + g, c3 = (j + 3) * 8 + g;
        vf4 v0 = __builtin_nontemporal_load(
            (const vf4*)(x2 + (size_t)(b * C1 + (c0 - C1)) * HW) + off);
        vf4 v1 = __builtin_nontemporal_load(
            (const vf4*)(x2 + (size_t)(b * C1 + (c1 - C1)) * HW) + off);
        vf4 v2 = __builtin_nontemporal_load(
            (const vf4*)(x2 + (size_t)(b * C1 + (c2 - C1)) * HW) + off);
        vf4 v3 = __builtin_nontemporal_load(
            (const vf4*)(x2 + (size_t)(b * C1 + (c3 - C1)) * HW) + off);
        t0 += v0; t1 += v1; t2 += v2; t3 += v3;
        float h0 = (v0.x + v0.y) + (v0.z + v0.w);
        float h1 = (v1.x + v1.y) + (v1.z + v1.w);
        float h2 = (v2.x + v2.y) + (v2.z + v2.w);
        float h3 = (v3.x + v3.y) + (v3.z + v3.w);
        #pragma unroll
        for (int s = 16; s > 0; s >>= 1) {
            h0 += __shfl_down(h0, s, 32);
            h1 += __shfl_down(h1, s, 32);
            h2 += __shfl_down(h2, s, 32);
            h3 += __shfl_down(h3, s, 32);
        }
        if (slot == 0) { pp[c0] = h0; pp[c1] = h1; pp[c2] = h2; pp[c3] = h3; }
    }

    __shared__ vf4 red[8][32];
    red[g][slot] = (t0 + t1) + (t2 + t3);
    __syncthreads();
    if (g == 0) {
        vf4 r = (vf4)(0.f);
        #pragma unroll
        for (int gg = 0; gg < 8; ++gg) r += red[gg][slot];
        ((vf4*)(total + (size_t)b * HW))[off] = r;
    }
}

// ---------------------------------------------------------------------------
// K2: per-batch stable descending rank-sort (single dispatch, 16 blocks).
// ---------------------------------------------------------------------------
__global__ __launch_bounds__(512) void sort_kernel(
    const float* __restrict__ partials, int* __restrict__ idx)
{
    int b = blockIdx.x;
    int t = threadIdx.x;
    const float* pp = partials + (size_t)b * TCHUNK * C2 + t;
    float v = 0.f;
    #pragma unroll
    for (int ch = 0; ch < TCHUNK; ++ch) v += pp[ch * C2];
    __shared__ float sp[C2];
    sp[t] = v;
    __syncthreads();
    int rank = 0;
    for (int j = 0; j < C2; ++j) {
        float u = sp[j];
        rank += (u > v) || (u == v && j < t);
    }
    idx[b * C2 + rank] = t;
}

// ---------------------------------------------------------------------------
// K3: output. Head-channel loads: x1 normal (L2/L3-warm from K1),
// x2 NT (cold fast path). NT stores (don't evict inputs).
// Channel k-1 = total - head_sum.
// ---------------------------------------------------------------------------
__global__ __launch_bounds__(256) void output_kernel(
    const float* __restrict__ x1, const float* __restrict__ x2,
    const int* __restrict__ idx, const float* __restrict__ total,
    float* __restrict__ out, int k)
{
    int bid   = blockIdx.x;
    int b     = bid / TCHUNK;
    int chunk = bid % TCHUNK;
    int t     = threadIdx.x;
    int g     = t >> 5;
    int slot  = t & 31;
    int off   = chunk * 32 + slot;
    int nh    = k - 1;

    __shared__ int ch[C2 / 2];
    __shared__ vf4 red[8][32];
    for (int i = t; i < nh; i += 256) ch[i] = idx[b * C2 + i];
    __syncthreads();

    vf4 a0 = (vf4)(0.f), a1 = (vf4)(0.f), a2 = (vf4)(0.f), a3 = (vf4)(0.f);
    const size_t ob = (size_t)b * k;
    int r = g;
    for (; r + 24 < nh; r += 32) {
        int c0 = ch[r], c1 = ch[r + 8], c2 = ch[r + 16], c3 = ch[r + 24];
        vf4 v0 = load_chan(x1, x2, b, c0, off);
        vf4 v1 = load_chan(x1, x2, b, c1, off);
        vf4 v2 = load_chan(x1, x2, b, c2, off);
        vf4 v3 = load_chan(x1, x2, b, c3, off);
        __builtin_nontemporal_store(v0, (vf4*)(out + (ob + r     ) * HW) + off);
        __builtin_nontemporal_store(v1, (vf4*)(out + (ob + r +  8) * HW) + off);
        __builtin_nontemporal_store(v2, (vf4*)(out + (ob + r + 16) * HW) + off);
        __builtin_nontemporal_store(v3, (vf4*)(out + (ob + r + 24) * HW) + off);
        a0 += v0; a1 += v1; a2 += v2; a3 += v3;
    }
    for (; r < nh; r += 8) {
        int c0 = ch[r];
        vf4 v0 = load_chan(x1, x2, b, c0, off);
        __builtin_nontemporal_store(v0, (vf4*)(out + (ob + r) * HW) + off);
        a0 += v0;
    }

    red[g][slot] = (a0 + a1) + (a2 + a3);
    __syncthreads();
    if (g == 0) {
        vf4 hsum = (vf4)(0.f);
        #pragma unroll
        for (int gg = 0; gg < 8; ++gg) hsum += red[gg][slot];
        vf4 tt = ((const vf4*)(total + (size_t)b * HW))[off];
        __builtin_nontemporal_store(tt - hsum,
                                    (vf4*)(out + (ob + (k - 1)) * HW) + off);
    }
}

// ---------------------------------------------------------------------------
extern "C" void kernel_launch(void* const* d_in, const int* in_sizes, int n_in,
                              void* d_out, int out_size, void* d_ws, size_t ws_size,
                              hipStream_t stream)
{
    const float* x1 = (const float*)d_in[0];
    const float* x2 = (const float*)d_in[1];
    float* out = (float*)d_out;

    int k = out_size / (B * HW);               // = 256

    int*   idx      = (int*)d_ws;
    float* total    = (float*)((char*)d_ws + B * C2 * sizeof(int));
    float* partials = total + (size_t)B * HW;

    reduce_kernel<<<B * TCHUNK, 256, 0, stream>>>(x1, x2, total, partials);
    sort_kernel<<<B, 512, 0, stream>>>(partials, idx);
    output_kernel<<<B * TCHUNK, 256, 0, stream>>>(x1, x2, idx, total, out, k);
}

// Round 16
// 63.698 us; speedup vs baseline: 1.1605x; 1.0306x over previous
//
#include <hip/hip_runtime.h>

#define B   16
#define C1  256          // channels per input
#define C2  512          // total channels after concat
#define HW  4096         // 64*64 pixels per channel
#define TCHUNK 32        // 128-pixel chunks per image

typedef float vf4 __attribute__((ext_vector_type(4)));

__device__ __forceinline__ const vf4* chan_base(
    const float* __restrict__ x1, const float* __restrict__ x2, int b, int c)
{
    return (const vf4*)((c < C1) ? (x1 + (size_t)(b * C1 + c) * HW)
                                 : (x2 + (size_t)(b * C1 + (c - C1)) * HW));
}

// ---------------------------------------------------------------------------
// K1: reduce with NORMAL (allocating) loads. Pays the ~2.9 TB/s cold
// allocating-read wall once, leaving inputs L2/L3-warm so K3's head
// re-read runs ~10 TB/s. (Measured best corner: 63.2 us total, round 12.)
// ---------------------------------------------------------------------------
__global__ __launch_bounds__(256) void reduce_kernel(
    const float* __restrict__ x1, const float* __restrict__ x2,
    float* __restrict__ total, float* __restrict__ partials)
{
    int bid   = blockIdx.x;
    int b     = bid / TCHUNK;
    int chunk = bid % TCHUNK;
    int t     = threadIdx.x;
    int g     = t >> 5;
    int slot  = t & 31;
    int off   = chunk * 32 + slot;

    float* pp = partials + (size_t)(b * TCHUNK + chunk) * C2;
    vf4 t0 = (vf4)(0.f), t1 = (vf4)(0.f), t2 = (vf4)(0.f), t3 = (vf4)(0.f);

    for (int j = 0; j < 64; j += 4) {
        int c0 = (j + 0) * 8 + g, c1 = (j + 1) * 8 + g;
        int c2 = (j + 2) * 8 + g, c3 = (j + 3) * 8 + g;
        vf4 v0 = chan_base(x1, x2, b, c0)[off];
        vf4 v1 = chan_base(x1, x2, b, c1)[off];
        vf4 v2 = chan_base(x1, x2, b, c2)[off];
        vf4 v3 = chan_base(x1, x2, b, c3)[off];
        t0 += v0; t1 += v1; t2 += v2; t3 += v3;
        float h0 = (v0.x + v0.y) + (v0.z + v0.w);
        float h1 = (v1.x + v1.y) + (v1.z + v1.w);
        float h2 = (v2.x + v2.y) + (v2.z + v2.w);
        float h3 = (v3.x + v3.y) + (v3.z + v3.w);
        #pragma unroll
        for (int s = 16; s > 0; s >>= 1) {
            h0 += __shfl_down(h0, s, 32);
            h1 += __shfl_down(h1, s, 32);
            h2 += __shfl_down(h2, s, 32);
            h3 += __shfl_down(h3, s, 32);
        }
        if (slot == 0) { pp[c0] = h0; pp[c1] = h1; pp[c2] = h2; pp[c3] = h3; }
    }

    __shared__ vf4 red[8][32];
    red[g][slot] = (t0 + t1) + (t2 + t3);
    __syncthreads();
    if (g == 0) {
        vf4 r = (vf4)(0.f);
        #pragma unroll
        for (int gg = 0; gg < 8; ++gg) r += red[gg][slot];
        ((vf4*)(total + (size_t)b * HW))[off] = r;
    }
}

// ---------------------------------------------------------------------------
// K2: per-batch stable descending rank-sort (single dispatch, 16 blocks).
// ---------------------------------------------------------------------------
__global__ __launch_bounds__(512) void sort_kernel(
    const float* __restrict__ partials, int* __restrict__ idx)
{
    int b = blockIdx.x;
    int t = threadIdx.x;
    const float* pp = partials + (size_t)b * TCHUNK * C2 + t;
    float v = 0.f;
    #pragma unroll
    for (int ch = 0; ch < TCHUNK; ++ch) v += pp[ch * C2];
    __shared__ float sp[C2];
    sp[t] = v;
    __syncthreads();
    int rank = 0;
    for (int j = 0; j < C2; ++j) {
        float u = sp[j];
        rank += (u > v) || (u == v && j < t);
    }
    idx[b * C2 + rank] = t;
}

// ---------------------------------------------------------------------------
// K3: output — NORMAL head loads (hit the lines K1 just allocated) +
// NONTEMPORAL stores (the 64 MB output stream must not evict the warm
// inputs). Channel k-1 = total - head_sum (tail never re-read).
// ---------------------------------------------------------------------------
__global__ __launch_bounds__(256) void output_kernel(
    const float* __restrict__ x1, const float* __restrict__ x2,
    const int* __restrict__ idx, const float* __restrict__ total,
    float* __restrict__ out, int k)
{
    int bid   = blockIdx.x;
    int b     = bid / TCHUNK;
    int chunk = bid % TCHUNK;
    int t     = threadIdx.x;
    int g     = t >> 5;
    int slot  = t & 31;
    int off   = chunk * 32 + slot;
    int nh    = k - 1;

    __shared__ int ch[C2 / 2];
    __shared__ vf4 red[8][32];
    for (int i = t; i < nh; i += 256) ch[i] = idx[b * C2 + i];
    __syncthreads();

    vf4 a0 = (vf4)(0.f), a1 = (vf4)(0.f), a2 = (vf4)(0.f), a3 = (vf4)(0.f);
    const size_t ob = (size_t)b * k;
    int r = g;
    for (; r + 24 < nh; r += 32) {
        int c0 = ch[r], c1 = ch[r + 8], c2 = ch[r + 16], c3 = ch[r + 24];
        vf4 v0 = chan_base(x1, x2, b, c0)[off];
        vf4 v1 = chan_base(x1, x2, b, c1)[off];
        vf4 v2 = chan_base(x1, x2, b, c2)[off];
        vf4 v3 = chan_base(x1, x2, b, c3)[off];
        __builtin_nontemporal_store(v0, (vf4*)(out + (ob + r     ) * HW) + off);
        __builtin_nontemporal_store(v1, (vf4*)(out + (ob + r +  8) * HW) + off);
        __builtin_nontemporal_store(v2, (vf4*)(out + (ob + r + 16) * HW) + off);
        __builtin_nontemporal_store(v3, (vf4*)(out + (ob + r + 24) * HW) + off);
        a0 += v0; a1 += v1; a2 += v2; a3 += v3;
    }
    for (; r < nh; r += 8) {
        int c0 = ch[r];
        vf4 v0 = chan_base(x1, x2, b, c0)[off];
        __builtin_nontemporal_store(v0, (vf4*)(out + (ob + r) * HW) + off);
        a0 += v0;
    }

    red[g][slot] = (a0 + a1) + (a2 + a3);
    __syncthreads();
    if (g == 0) {
        vf4 hsum = (vf4)(0.f);
        #pragma unroll
        for (int gg = 0; gg < 8; ++gg) hsum += red[gg][slot];
        vf4 tt = ((const vf4*)(total + (size_t)b * HW))[off];
        __builtin_nontemporal_store(tt - hsum,
                                    (vf4*)(out + (ob + (k - 1)) * HW) + off);
    }
}

// ---------------------------------------------------------------------------
extern "C" void kernel_launch(void* const* d_in, const int* in_sizes, int n_in,
                              void* d_out, int out_size, void* d_ws, size_t ws_size,
                              hipStream_t stream)
{
    const float* x1 = (const float*)d_in[0];
    const float* x2 = (const float*)d_in[1];
    float* out = (float*)d_out;

    int k = out_size / (B * HW);               // = 256

    int*   idx      = (int*)d_ws;
    float* total    = (float*)((char*)d_ws + B * C2 * sizeof(int));
    float* partials = total + (size_t)B * HW;

    reduce_kernel<<<B * TCHUNK, 256, 0, stream>>>(x1, x2, total, partials);
    sort_kernel<<<B, 512, 0, stream>>>(partials, idx);
    output_kernel<<<B * TCHUNK, 256, 0, stream>>>(x1, x2, idx, total, out, k);
}